// Round 1
// baseline (5858.139 us; speedup 1.0000x reference)
//
#include <hip/hip_runtime.h>
#include <hip/hip_cooperative_groups.h>
#include <math.h>

namespace cg = cooperative_groups;

#define B_ 64
#define T_ 128
#define I_ 1024
#define H_ 4096

#define RNN_BLOCKS 256
#define RNN_THREADS 1024
#define ROWS_PER_BLOCK (H_ / RNN_BLOCKS)  // 16 rows per block, 1 per wave

// ---------------- transpose x (B,T,I) -> xT (T,I,B) ----------------
__global__ void transpose_x(const float* __restrict__ x, float* __restrict__ xT) {
    __shared__ float tile[32][33];
    int t  = blockIdx.z;
    int i0 = blockIdx.x * 32;
    int b0 = blockIdx.y * 32;
    int tx = threadIdx.x, ty = threadIdx.y;
    // read x[b0+ty, t, i0+tx] (coalesced along i)
    tile[ty][tx] = x[(size_t)(b0 + ty) * T_ * I_ + (size_t)t * I_ + i0 + tx];
    __syncthreads();
    // write xT[t, i0+ty, b0+tx] (coalesced along b)
    xT[(size_t)t * I_ * B_ + (size_t)(i0 + ty) * B_ + b0 + tx] = tile[tx][ty];
}

// ---------------- CSR build: histogram, scan, scatter ----------------
__global__ void hist_rows(const int* __restrict__ rows, int nnz, int* __restrict__ counts) {
    int k = blockIdx.x * blockDim.x + threadIdx.x;
    if (k < nnz) atomicAdd(&counts[rows[k]], 1);
}

// single block of 64 threads, n must be divisible by 64 (n = 4096)
__global__ void scan_rows(const int* __restrict__ counts, int* __restrict__ rp, int n) {
    int lane = threadIdx.x;      // 0..63
    int chunk = n / 64;
    int base = lane * chunk;
    int s = 0;
    for (int j = 0; j < chunk; ++j) s += counts[base + j];
    int pre = s;
    for (int off = 1; off < 64; off <<= 1) {
        int up = __shfl_up(pre, off, 64);
        if (lane >= off) pre += up;
    }
    int run = pre - s;  // exclusive prefix of this lane's chunk
    for (int j = 0; j < chunk; ++j) { rp[base + j] = run; run += counts[base + j]; }
    if (lane == 63) rp[n] = run;
}

__global__ void scatter_csr(const int* __restrict__ rows, const int* __restrict__ cols,
                            const float* __restrict__ vals, int nnz,
                            const int* __restrict__ rp, int* __restrict__ cursor,
                            int* __restrict__ cols_s, float* __restrict__ vals_s) {
    int k = blockIdx.x * blockDim.x + threadIdx.x;
    if (k < nnz) {
        int r = rows[k];
        int pos = atomicAdd(&cursor[r], 1);
        int dst = rp[r] + pos;
        cols_s[dst] = cols[k];
        vals_s[dst] = vals[k];
    }
}

// ---------------- persistent recurrence kernel ----------------
__global__ __launch_bounds__(RNN_THREADS)
void rnn_steps(const float* __restrict__ xT,
               const int* __restrict__ ihp, const int* __restrict__ ihc, const float* __restrict__ ihv,
               const int* __restrict__ hhp, const int* __restrict__ hhc, const float* __restrict__ hhv,
               const float* __restrict__ bias,
               float* __restrict__ h0, float* __restrict__ h1,
               float* __restrict__ out) {
    cg::grid_group grid = cg::this_grid();
    __shared__ float tile[ROWS_PER_BLOCK][B_ + 1];  // +1 pad: conflict-light transpose read

    int tid  = threadIdx.x;
    int wave = tid >> 6;   // 0..15
    int lane = tid & 63;   // batch column
    int r = blockIdx.x * ROWS_PER_BLOCK + wave;   // this wave's row, fixed for all t

    // zero the initial hidden state h0
    {
        int total  = H_ * B_;
        int stride = gridDim.x * blockDim.x;
        for (int idx = blockIdx.x * blockDim.x + tid; idx < total; idx += stride) h0[idx] = 0.0f;
    }
    grid.sync();

    float bias_r  = bias[r];
    int   ih_beg  = ihp[r], ih_end = ihp[r + 1];
    int   hh_beg  = hhp[r], hh_end = hhp[r + 1];

    for (int t = 0; t < T_; ++t) {
        const float* __restrict__ hprev = (t & 1) ? h1 : h0;
        float*       __restrict__ hnew  = (t & 1) ? h0 : h1;
        const float* __restrict__ xt = xT + (size_t)t * I_ * B_;

        float acc  = bias_r;
        float acc2 = 0.0f;

        // ---- ih SpMM row: gather x_t columns ----
        int k = ih_beg;
        for (; k + 8 <= ih_end; k += 8) {
            int c0 = ihc[k+0], c1 = ihc[k+1], c2 = ihc[k+2], c3 = ihc[k+3];
            int c4 = ihc[k+4], c5 = ihc[k+5], c6 = ihc[k+6], c7 = ihc[k+7];
            float v0 = ihv[k+0], v1 = ihv[k+1], v2 = ihv[k+2], v3 = ihv[k+3];
            float v4 = ihv[k+4], v5 = ihv[k+5], v6 = ihv[k+6], v7 = ihv[k+7];
            float g0 = xt[c0*B_ + lane], g1 = xt[c1*B_ + lane];
            float g2 = xt[c2*B_ + lane], g3 = xt[c3*B_ + lane];
            float g4 = xt[c4*B_ + lane], g5 = xt[c5*B_ + lane];
            float g6 = xt[c6*B_ + lane], g7 = xt[c7*B_ + lane];
            acc  += v0*g0; acc2 += v1*g1; acc  += v2*g2; acc2 += v3*g3;
            acc  += v4*g4; acc2 += v5*g5; acc  += v6*g6; acc2 += v7*g7;
        }
        for (; k < ih_end; ++k) acc += ihv[k] * xt[ihc[k]*B_ + lane];

        // ---- hh SpMM row: gather h_prev columns ----
        k = hh_beg;
        for (; k + 8 <= hh_end; k += 8) {
            int c0 = hhc[k+0], c1 = hhc[k+1], c2 = hhc[k+2], c3 = hhc[k+3];
            int c4 = hhc[k+4], c5 = hhc[k+5], c6 = hhc[k+6], c7 = hhc[k+7];
            float v0 = hhv[k+0], v1 = hhv[k+1], v2 = hhv[k+2], v3 = hhv[k+3];
            float v4 = hhv[k+4], v5 = hhv[k+5], v6 = hhv[k+6], v7 = hhv[k+7];
            float g0 = hprev[c0*B_ + lane], g1 = hprev[c1*B_ + lane];
            float g2 = hprev[c2*B_ + lane], g3 = hprev[c3*B_ + lane];
            float g4 = hprev[c4*B_ + lane], g5 = hprev[c5*B_ + lane];
            float g6 = hprev[c6*B_ + lane], g7 = hprev[c7*B_ + lane];
            acc  += v0*g0; acc2 += v1*g1; acc  += v2*g2; acc2 += v3*g3;
            acc  += v4*g4; acc2 += v5*g5; acc  += v6*g6; acc2 += v7*g7;
        }
        for (; k < hh_end; ++k) acc += hhv[k] * hprev[hhc[k]*B_ + lane];

        float h = tanhf(acc + acc2);
        hnew[r * B_ + lane] = h;
        tile[wave][lane] = h;
        __syncthreads();

        // write out[b, t, r] with 64B-contiguous segments along r
        {
            int b = tid >> 4;       // 0..63
            int j = tid & 15;       // 0..15 -> row within block
            out[(size_t)b * T_ * H_ + (size_t)t * H_ + blockIdx.x * ROWS_PER_BLOCK + j] = tile[j][b];
        }
        grid.sync();  // h visibility for next step + protects tile reuse
    }
}

// ---------------- host launch ----------------
extern "C" void kernel_launch(void* const* d_in, const int* in_sizes, int n_in,
                              void* d_out, int out_size, void* d_ws, size_t ws_size,
                              hipStream_t stream) {
    const float* x       = (const float*)d_in[0];
    const float* ih_vals = (const float*)d_in[1];
    const float* hh_vals = (const float*)d_in[2];
    const float* hh_bias = (const float*)d_in[3];
    const int*   ih_rows = (const int*)d_in[4];
    const int*   ih_cols = (const int*)d_in[5];
    const int*   hh_rows = (const int*)d_in[6];
    const int*   hh_cols = (const int*)d_in[7];
    float* out = (float*)d_out;

    const int nnz_ih = in_sizes[1];
    const int nnz_hh = in_sizes[2];

    char* ws = (char*)d_ws;
    size_t off = 0;
    auto alloc = [&](size_t bytes) -> void* {
        off = (off + 255) & ~(size_t)255;
        void* p = ws + off;
        off += bytes;
        return p;
    };

    float* xT       = (float*)alloc((size_t)T_ * I_ * B_ * sizeof(float));
    int*   ih_rp    = (int*)  alloc((H_ + 1) * sizeof(int));
    int*   hh_rp    = (int*)  alloc((H_ + 1) * sizeof(int));
    int*   zeros    = (int*)  alloc((size_t)4 * H_ * sizeof(int));  // counts/cursor x2
    int*   ih_cnt   = zeros;
    int*   ih_cur   = zeros + H_;
    int*   hh_cnt   = zeros + 2 * H_;
    int*   hh_cur   = zeros + 3 * H_;
    int*   ih_colss = (int*)  alloc((size_t)nnz_ih * sizeof(int));
    float* ih_valss = (float*)alloc((size_t)nnz_ih * sizeof(float));
    int*   hh_colss = (int*)  alloc((size_t)nnz_hh * sizeof(int));
    float* hh_valss = (float*)alloc((size_t)nnz_hh * sizeof(float));
    float* h0       = (float*)alloc((size_t)H_ * B_ * sizeof(float));
    float* h1       = (float*)alloc((size_t)H_ * B_ * sizeof(float));

    // zero counters/cursors
    hipMemsetAsync(zeros, 0, (size_t)4 * H_ * sizeof(int), stream);

    // transpose x -> xT
    transpose_x<<<dim3(I_ / 32, B_ / 32, T_), dim3(32, 32), 0, stream>>>(x, xT);

    // CSR build (ih)
    hist_rows<<<(nnz_ih + 255) / 256, 256, 0, stream>>>(ih_rows, nnz_ih, ih_cnt);
    scan_rows<<<1, 64, 0, stream>>>(ih_cnt, ih_rp, H_);
    scatter_csr<<<(nnz_ih + 255) / 256, 256, 0, stream>>>(ih_rows, ih_cols, ih_vals, nnz_ih,
                                                          ih_rp, ih_cur, ih_colss, ih_valss);
    // CSR build (hh)
    hist_rows<<<(nnz_hh + 255) / 256, 256, 0, stream>>>(hh_rows, nnz_hh, hh_cnt);
    scan_rows<<<1, 64, 0, stream>>>(hh_cnt, hh_rp, H_);
    scatter_csr<<<(nnz_hh + 255) / 256, 256, 0, stream>>>(hh_rows, hh_cols, hh_vals, nnz_hh,
                                                          hh_rp, hh_cur, hh_colss, hh_valss);

    // persistent cooperative recurrence
    const float* bias = hh_bias;
    void* kargs[] = {
        (void*)&xT,
        (void*)&ih_rp, (void*)&ih_colss, (void*)&ih_valss,
        (void*)&hh_rp, (void*)&hh_colss, (void*)&hh_valss,
        (void*)&bias,
        (void*)&h0, (void*)&h1,
        (void*)&out,
    };
    hipLaunchCooperativeKernel((const void*)rnn_steps, dim3(RNN_BLOCKS), dim3(RNN_THREADS),
                               kargs, 0, stream);
}

// Round 2
// 3928.868 us; speedup vs baseline: 1.4911x; 1.4911x over previous
//
#include <hip/hip_runtime.h>
#include <hip/hip_cooperative_groups.h>
#include <math.h>

namespace cg = cooperative_groups;

#define B_ 64
#define T_ 128
#define I_ 1024
#define H_ 4096
#define XCDS 8

#define RNN_BLOCKS 256
#define RNN_THREADS 1024

// ---------------- transpose x (B,T,I) -> xT2 (T, 8, I, 8) ----------------
// xT2[((t*8 + bg)*I + i)*8 + bs] = x[bg*8+bs][t][i]
__global__ void transpose_x(const float* __restrict__ x, float* __restrict__ xT2) {
    __shared__ float lds[8][129];
    int t  = blockIdx.z;
    int bg = blockIdx.y;
    int i0 = blockIdx.x * 128;
    int tx = threadIdx.x;   // 0..127
    int ty = threadIdx.y;   // 0..7
    int b = bg * 8 + ty;
    lds[ty][tx] = x[(size_t)b * T_ * I_ + (size_t)t * I_ + i0 + tx];
    __syncthreads();
    int n  = ty * 128 + tx;
    int ii = n >> 3;
    int bs = n & 7;
    xT2[(((size_t)t * 8 + bg) * I_ + i0 + ii) * 8 + bs] = lds[bs][ii];
}

// ---------------- CSR build: histogram, scan, scatter ----------------
__global__ void hist_rows(const int* __restrict__ rows, int nnz, int* __restrict__ counts) {
    int k = blockIdx.x * blockDim.x + threadIdx.x;
    if (k < nnz) atomicAdd(&counts[rows[k]], 1);
}

__global__ void scan_rows(const int* __restrict__ counts, int* __restrict__ rp, int n) {
    int lane = threadIdx.x;      // 0..63
    int chunk = n / 64;
    int base = lane * chunk;
    int s = 0;
    for (int j = 0; j < chunk; ++j) s += counts[base + j];
    int pre = s;
    for (int off = 1; off < 64; off <<= 1) {
        int up = __shfl_up(pre, off, 64);
        if (lane >= off) pre += up;
    }
    int run = pre - s;
    for (int j = 0; j < chunk; ++j) { rp[base + j] = run; run += counts[base + j]; }
    if (lane == 63) rp[n] = run;
}

__global__ void scatter_csr(const int* __restrict__ rows, const int* __restrict__ cols,
                            const float* __restrict__ vals, int nnz,
                            const int* __restrict__ rp, int* __restrict__ cursor,
                            int* __restrict__ cols_s, float* __restrict__ vals_s) {
    int k = blockIdx.x * blockDim.x + threadIdx.x;
    if (k < nnz) {
        int r = rows[k];
        int pos = atomicAdd(&cursor[r], 1);
        int dst = rp[r] + pos;
        cols_s[dst] = cols[k];
        vals_s[dst] = vals[k];
    }
}

// L1-bypassing load (sc0): reads XCD-local L2, which holds the freshest h
// (producers drain stores to L2 at __syncthreads before barrier arrival).
__device__ __forceinline__ void gather8_sc0(const float* const p[8], float g[8]) {
    asm volatile(
        "global_load_dword %0, %8, off sc0\n\t"
        "global_load_dword %1, %9, off sc0\n\t"
        "global_load_dword %2, %10, off sc0\n\t"
        "global_load_dword %3, %11, off sc0\n\t"
        "global_load_dword %4, %12, off sc0\n\t"
        "global_load_dword %5, %13, off sc0\n\t"
        "global_load_dword %6, %14, off sc0\n\t"
        "global_load_dword %7, %15, off sc0\n\t"
        "s_waitcnt vmcnt(0)"
        : "=&v"(g[0]), "=&v"(g[1]), "=&v"(g[2]), "=&v"(g[3]),
          "=&v"(g[4]), "=&v"(g[5]), "=&v"(g[6]), "=&v"(g[7])
        : "v"(p[0]), "v"(p[1]), "v"(p[2]), "v"(p[3]),
          "v"(p[4]), "v"(p[5]), "v"(p[6]), "v"(p[7]));
}

// ---------------- persistent XCD-local recurrence kernel ----------------
__global__ __launch_bounds__(RNN_THREADS, 4)
void rnn_steps(const float* __restrict__ xT2,
               const int* __restrict__ ihp, const int* __restrict__ ihc, const float* __restrict__ ihv,
               const int* __restrict__ hhp, const int* __restrict__ hhc, const float* __restrict__ hhv,
               const float* __restrict__ bias,
               float* __restrict__ hbuf,     // [8 groups][2 parity][H*8]
               int* __restrict__ regcnt,     // [8]
               int* __restrict__ barcnt,     // [8*32] (one line per XCD)
               int* __restrict__ bargen,     // [8*32]
               int* __restrict__ owncnt,     // [8]
               int* __restrict__ owngrp,     // [8*8]
               float* __restrict__ out) {
    cg::grid_group grid = cg::this_grid();
    __shared__ int sh_xcd, sh_slot;
    int tid = threadIdx.x;

    // --- register this block on its physical XCD ---
    if (tid == 0) {
        int x;
        asm volatile("s_getreg_b32 %0, hwreg(HW_REG_XCC_ID)" : "=s"(x));
        x &= 7;
        sh_xcd = x;
        sh_slot = __hip_atomic_fetch_add(&regcnt[x], 1, __ATOMIC_RELAXED,
                                         __HIP_MEMORY_SCOPE_AGENT);
    }
    // zero all h buffers (grid-stride)
    {
        int total = XCDS * 2 * H_ * 8;
        for (int idx = blockIdx.x * blockDim.x + tid; idx < total;
             idx += gridDim.x * blockDim.x) hbuf[idx] = 0.0f;
    }
    __syncthreads();
    int xcd = sh_xcd, slot = sh_slot;
    grid.sync();

    // --- group ownership: group j -> XCD j if populated, else adopted ---
    if (blockIdx.x == 0 && tid == 0) {
        int list[XCDS]; int nz = 0;
        for (int j = 0; j < XCDS; ++j) {
            owncnt[j] = 0;
            if (__hip_atomic_load(&regcnt[j], __ATOMIC_RELAXED,
                                  __HIP_MEMORY_SCOPE_AGENT) > 0) list[nz++] = j;
        }
        int rr = 0;
        for (int j = 0; j < XCDS; ++j) {
            int present = __hip_atomic_load(&regcnt[j], __ATOMIC_RELAXED,
                                            __HIP_MEMORY_SCOPE_AGENT) > 0;
            int owner = present ? j : list[rr++ % nz];
            owngrp[owner * 8 + owncnt[owner]] = j;
            owncnt[owner] += 1;
        }
    }
    grid.sync();

    int nblk  = __hip_atomic_load(&regcnt[xcd], __ATOMIC_RELAXED, __HIP_MEMORY_SCOPE_AGENT);
    int nwaves = nblk * (RNN_THREADS / 64);
    int nown  = owncnt[xcd];
    int wave  = tid >> 6;
    int lane  = tid & 63;
    int rs    = lane >> 3;   // row within 8-row group
    int bs    = lane & 7;    // batch col within group
    int mywave = slot * (RNN_THREADS / 64) + wave;

    int* bc = &barcnt[xcd * 32];
    int* bg = &bargen[xcd * 32];

    for (int t = 0; t < T_; ++t) {
        for (int oi = 0; oi < nown; ++oi) {
            int grp = owngrp[xcd * 8 + oi];
            float* gbuf  = hbuf + (size_t)grp * 2 * H_ * 8;
            const float* hprev = gbuf + (size_t)(t & 1) * H_ * 8;
            float*       hnew  = gbuf + (size_t)((t & 1) ^ 1) * H_ * 8;
            const float* xt = xT2 + ((size_t)t * 8 + grp) * I_ * 8;

            for (int g = mywave; g < H_ / 8; g += nwaves) {
                int r = g * 8 + rs;
                float acc = bias[r];
                int ib = ihp[r], ie = ihp[r + 1];
                int hb = hhp[r], he = hhp[r + 1];
                int li = ie - ib, lh = he - hb;
                #pragma unroll
                for (int off = 32; off; off >>= 1) {
                    li = max(li, __shfl_xor(li, off));
                    lh = max(lh, __shfl_xor(lh, off));
                }

                // ---- ih: gather x_t (read-only data, plain loads) ----
                int ni = (li + 7) & ~7;
                for (int i = 0; i < ni; i += 8) {
                    float xv[8], vv[8];
                    #pragma unroll
                    for (int u = 0; u < 8; ++u) {
                        int k = ib + i + u;
                        int kc = (k < ie) ? k : (ie > 0 ? ie - 1 : 0);
                        int c = ihc[kc] & (I_ - 1);
                        vv[u] = (k < ie) ? ihv[kc] : 0.0f;
                        xv[u] = xt[c * 8 + bs];
                    }
                    #pragma unroll
                    for (int u = 0; u < 8; ++u) acc += vv[u] * xv[u];
                }

                // ---- hh: gather h_prev via sc0 (L1-bypass, L2-hit) ----
                int nh = (lh + 7) & ~7;
                for (int i = 0; i < nh; i += 8) {
                    const float* p[8]; float vv[8]; float gv[8];
                    #pragma unroll
                    for (int u = 0; u < 8; ++u) {
                        int k = hb + i + u;
                        int kc = (k < he) ? k : (he > 0 ? he - 1 : 0);
                        int c = hhc[kc] & (H_ - 1);
                        vv[u] = (k < he) ? hhv[kc] : 0.0f;
                        p[u] = hprev + (size_t)c * 8 + bs;
                    }
                    gather8_sc0(p, gv);
                    #pragma unroll
                    for (int u = 0; u < 8; ++u) acc += vv[u] * gv[u];
                }

                float h = tanhf(acc);
                hnew[(size_t)r * 8 + bs] = h;
                out[(size_t)(grp * 8 + bs) * T_ * H_ + (size_t)t * H_ + r] = h;
            }
        }

        // ---- per-XCD barrier: no cache maintenance, relaxed atomics ----
        __syncthreads();  // drains this block's stores to L2 (vmcnt(0) before s_barrier)
        if (tid == 0) {
            asm volatile("s_waitcnt vmcnt(0)" ::: "memory");
            int target = t + 1;
            int old = __hip_atomic_fetch_add(bc, 1, __ATOMIC_RELAXED,
                                             __HIP_MEMORY_SCOPE_AGENT);
            if (old == nblk - 1) {
                __hip_atomic_store(bc, 0, __ATOMIC_RELAXED, __HIP_MEMORY_SCOPE_AGENT);
                __hip_atomic_store(bg, target, __ATOMIC_RELAXED, __HIP_MEMORY_SCOPE_AGENT);
            } else {
                while (__hip_atomic_load(bg, __ATOMIC_RELAXED,
                                         __HIP_MEMORY_SCOPE_AGENT) < target) {
                    __builtin_amdgcn_s_sleep(2);
                }
            }
        }
        __syncthreads();
    }
}

// ---------------- host launch ----------------
extern "C" void kernel_launch(void* const* d_in, const int* in_sizes, int n_in,
                              void* d_out, int out_size, void* d_ws, size_t ws_size,
                              hipStream_t stream) {
    const float* x       = (const float*)d_in[0];
    const float* ih_vals = (const float*)d_in[1];
    const float* hh_vals = (const float*)d_in[2];
    const float* hh_bias = (const float*)d_in[3];
    const int*   ih_rows = (const int*)d_in[4];
    const int*   ih_cols = (const int*)d_in[5];
    const int*   hh_rows = (const int*)d_in[6];
    const int*   hh_cols = (const int*)d_in[7];
    float* out = (float*)d_out;

    const int nnz_ih = in_sizes[1];
    const int nnz_hh = in_sizes[2];

    char* ws = (char*)d_ws;
    size_t off = 0;
    auto alloc = [&](size_t bytes) -> void* {
        off = (off + 255) & ~(size_t)255;
        void* p = ws + off;
        off += bytes;
        return p;
    };

    float* xT2   = (float*)alloc((size_t)T_ * 8 * I_ * 8 * sizeof(float));
    int*   ih_rp = (int*)  alloc((H_ + 1) * sizeof(int));
    int*   hh_rp = (int*)  alloc((H_ + 1) * sizeof(int));

    // single contiguous zeroed int region
    const int ZINTS = 4 * H_ + 64 + 8 * 32 + 8 * 32 + 8 + 64;
    int* zbase  = (int*)alloc((size_t)ZINTS * sizeof(int));
    int* ih_cnt = zbase;
    int* ih_cur = zbase + H_;
    int* hh_cnt = zbase + 2 * H_;
    int* hh_cur = zbase + 3 * H_;
    int* regcnt = zbase + 4 * H_;          // 64 ints reserved
    int* barcnt = regcnt + 64;             // 8*32
    int* bargen = barcnt + 8 * 32;         // 8*32
    int* owncnt = bargen + 8 * 32;         // 8
    int* owngrp = owncnt + 8;              // 64

    int*   ih_colss = (int*)  alloc((size_t)nnz_ih * sizeof(int));
    float* ih_valss = (float*)alloc((size_t)nnz_ih * sizeof(float));
    int*   hh_colss = (int*)  alloc((size_t)nnz_hh * sizeof(int));
    float* hh_valss = (float*)alloc((size_t)nnz_hh * sizeof(float));
    float* hbuf     = (float*)alloc((size_t)XCDS * 2 * H_ * 8 * sizeof(float));

    hipMemsetAsync(zbase, 0, (size_t)ZINTS * sizeof(int), stream);

    transpose_x<<<dim3(I_ / 128, 8, T_), dim3(128, 8), 0, stream>>>(x, xT2);

    hist_rows<<<(nnz_ih + 255) / 256, 256, 0, stream>>>(ih_rows, nnz_ih, ih_cnt);
    scan_rows<<<1, 64, 0, stream>>>(ih_cnt, ih_rp, H_);
    scatter_csr<<<(nnz_ih + 255) / 256, 256, 0, stream>>>(ih_rows, ih_cols, ih_vals, nnz_ih,
                                                          ih_rp, ih_cur, ih_colss, ih_valss);
    hist_rows<<<(nnz_hh + 255) / 256, 256, 0, stream>>>(hh_rows, nnz_hh, hh_cnt);
    scan_rows<<<1, 64, 0, stream>>>(hh_cnt, hh_rp, H_);
    scatter_csr<<<(nnz_hh + 255) / 256, 256, 0, stream>>>(hh_rows, hh_cols, hh_vals, nnz_hh,
                                                          hh_rp, hh_cur, hh_colss, hh_valss);

    const float* bias = hh_bias;
    void* kargs[] = {
        (void*)&xT2,
        (void*)&ih_rp, (void*)&ih_colss, (void*)&ih_valss,
        (void*)&hh_rp, (void*)&hh_colss, (void*)&hh_valss,
        (void*)&bias,
        (void*)&hbuf,
        (void*)&regcnt, (void*)&barcnt, (void*)&bargen,
        (void*)&owncnt, (void*)&owngrp,
        (void*)&out,
    };
    hipLaunchCooperativeKernel((const void*)rnn_steps, dim3(RNN_BLOCKS), dim3(RNN_THREADS),
                               kargs, 0, stream);
}

// Round 3
// 1880.818 us; speedup vs baseline: 3.1147x; 2.0889x over previous
//
#include <hip/hip_runtime.h>
#include <hip/hip_cooperative_groups.h>
#include <math.h>

namespace cg = cooperative_groups;

#define B_ 64
#define T_ 128
#define I_ 1024
#define H_ 4096
#define XCDS 8

#define RNN_BLOCKS 256
#define RNN_THREADS 1024

// ---------------- helpers ----------------
__device__ __forceinline__ unsigned short f2bf(float f) {
    unsigned int u = __float_as_uint(f);
    unsigned int r = (u + 0x7fffu + ((u >> 16) & 1u)) >> 16;
    return (unsigned short)r;
}

__device__ __forceinline__ void load4x16_sc0(const float* p0, const float* p1,
                                             const float* p2, const float* p3,
                                             float4& a, float4& b, float4& c, float4& d) {
    asm volatile(
        "global_load_dwordx4 %0, %4, off sc0\n\t"
        "global_load_dwordx4 %1, %5, off sc0\n\t"
        "global_load_dwordx4 %2, %6, off sc0\n\t"
        "global_load_dwordx4 %3, %7, off sc0\n\t"
        "s_waitcnt vmcnt(0)"
        : "=&v"(a), "=&v"(b), "=&v"(c), "=&v"(d)
        : "v"(p0), "v"(p1), "v"(p2), "v"(p3));
}

// ---------------- transpose x (B,T,I) -> xT2 (T, 8, I, 8) ----------------
__global__ void transpose_x(const float* __restrict__ x, float* __restrict__ xT2) {
    __shared__ float lds[8][129];
    int t  = blockIdx.z;
    int bg = blockIdx.y;
    int i0 = blockIdx.x * 128;
    int tx = threadIdx.x;   // 0..127
    int ty = threadIdx.y;   // 0..7
    int b = bg * 8 + ty;
    lds[ty][tx] = x[(size_t)b * T_ * I_ + (size_t)t * I_ + i0 + tx];
    __syncthreads();
    int n  = ty * 128 + tx;
    int ii = n >> 3;
    int bs = n & 7;
    xT2[(((size_t)t * 8 + bg) * I_ + i0 + ii) * 8 + bs] = lds[bs][ii];
}

// ---------------- CSR build ----------------
__global__ void hist_rows(const int* __restrict__ rows, int nnz, int* __restrict__ counts) {
    int k = blockIdx.x * blockDim.x + threadIdx.x;
    if (k < nnz) atomicAdd(&counts[rows[k]], 1);
}

__global__ void scan_rows(const int* __restrict__ counts, int* __restrict__ rp, int n) {
    int lane = threadIdx.x;      // 0..63
    int chunk = n / 64;
    int base = lane * chunk;
    int s = 0;
    for (int j = 0; j < chunk; ++j) s += counts[base + j];
    int pre = s;
    for (int off = 1; off < 64; off <<= 1) {
        int up = __shfl_up(pre, off, 64);
        if (lane >= off) pre += up;
    }
    int run = pre - s;
    for (int j = 0; j < chunk; ++j) { rp[base + j] = run; run += counts[base + j]; }
    if (lane == 63) rp[n] = run;
}

__global__ void scatter_pack(const int* __restrict__ rows, const int* __restrict__ cols,
                             const float* __restrict__ vals, int nnz,
                             const int* __restrict__ rp, int* __restrict__ cursor,
                             int2* __restrict__ pack) {
    int k = blockIdx.x * blockDim.x + threadIdx.x;
    if (k < nnz) {
        int r = rows[k];
        int pos = atomicAdd(&cursor[r], 1);
        pack[rp[r] + pos] = make_int2(cols[k], __float_as_int(vals[k]));
    }
}

// ---------------- kernel P: pre[t] = W_ih * x_t + bias  (bf16 out) ----------------
// grid: (128 rowchunks, 8 grps, T). block: 256 thr = 4 waves, wave = 1 row-group of 8 rows.
__global__ __launch_bounds__(256)
void precompute_ih(const float* __restrict__ xT2,
                   const int* __restrict__ rp, const int2* __restrict__ pack,
                   const float* __restrict__ bias,
                   unsigned short* __restrict__ pre) {
    int t   = blockIdx.z;
    int grp = blockIdx.y;
    int g   = blockIdx.x * 4 + (threadIdx.x >> 6);
    int lane = threadIdx.x & 63;
    int rs = lane >> 3;   // row within group
    int u  = lane & 7;    // position within window

    int r  = g * 8 + rs;
    int hb = rp[r], he = rp[r + 1];
    int len = he - hb;
    int lmax = len;
    lmax = max(lmax, __shfl_xor(lmax, 8));
    lmax = max(lmax, __shfl_xor(lmax, 16));
    lmax = max(lmax, __shfl_xor(lmax, 32));

    const float* xt = xT2 + ((size_t)t * 8 + grp) * I_ * 8;

    float a[8];
    #pragma unroll
    for (int j = 0; j < 8; ++j) a[j] = 0.0f;

    int kk = hb + u;
    for (int i = 0; i < lmax; i += 8, kk += 8) {
        int2 pk = make_int2(0, 0);
        if (i + u < len) pk = pack[kk];
        float v = __int_as_float(pk.y);
        const float* gp = xt + (size_t)pk.x * 8;
        float4 x0 = *(const float4*)(gp);
        float4 x1 = *(const float4*)(gp + 4);
        a[0] += v * x0.x; a[1] += v * x0.y; a[2] += v * x0.z; a[3] += v * x0.w;
        a[4] += v * x1.x; a[5] += v * x1.y; a[6] += v * x1.z; a[7] += v * x1.w;
    }
    #pragma unroll
    for (int off = 1; off <= 4; off <<= 1) {
        #pragma unroll
        for (int j = 0; j < 8; ++j) a[j] += __shfl_xor(a[j], off);
    }
    // lane (rs,u) outputs column u of row r
    float sel = (u == 0) ? a[0] : (u == 1) ? a[1] : (u == 2) ? a[2] : (u == 3) ? a[3]
              : (u == 4) ? a[4] : (u == 5) ? a[5] : (u == 6) ? a[6] : a[7];
    float p = sel + bias[r];
    int hf = u >> 2, cc = u & 3;
    pre[((size_t)(grp * 2 + hf) * T_ + t) * (H_ * 4) + (size_t)r * 4 + cc] = f2bf(p);
}

// ---------------- kernel R: persistent XCD-local recurrence ----------------
// hg layout: hg[((grp*2 + parity)*2 + half) * (H_*4)]
__global__ __launch_bounds__(RNN_THREADS, 1)
void rnn_steps(const int* __restrict__ hhp, const int2* __restrict__ hhpack,
               const unsigned short* __restrict__ pre,
               float* __restrict__ hg,
               int* __restrict__ regcnt, int* __restrict__ barcnt, int* __restrict__ bargen,
               int* __restrict__ owncnt, int* __restrict__ owngrp,
               float* __restrict__ out) {
    cg::grid_group grid = cg::this_grid();
    __shared__ __align__(16) float sh[H_ * 4];   // 64 KB: h_prev, 4 batch cols of this half

    int tid = threadIdx.x;
    if (tid == 0) {
        int x;
        asm volatile("s_getreg_b32 %0, hwreg(HW_REG_XCC_ID)" : "=s"(x));
        x &= 7;
        int slot = __hip_atomic_fetch_add(&regcnt[x], 1, __ATOMIC_RELAXED,
                                          __HIP_MEMORY_SCOPE_AGENT);
        sh[0] = __int_as_float(x);
        sh[1] = __int_as_float(slot);
    }
    __syncthreads();
    int xcd  = __float_as_int(sh[0]);
    int slot = __float_as_int(sh[1]);
    grid.sync();

    if (blockIdx.x == 0 && tid == 0) {
        int list[XCDS]; int nz = 0;
        for (int j = 0; j < XCDS; ++j) {
            owncnt[j] = 0;
            if (__hip_atomic_load(&regcnt[j], __ATOMIC_RELAXED,
                                  __HIP_MEMORY_SCOPE_AGENT) > 0) list[nz++] = j;
        }
        int rr = 0;
        for (int j = 0; j < XCDS; ++j) {
            int present = __hip_atomic_load(&regcnt[j], __ATOMIC_RELAXED,
                                            __HIP_MEMORY_SCOPE_AGENT) > 0;
            int owner = present ? j : list[rr++ % nz];
            owngrp[owner * 8 + owncnt[owner]] = j;
            owncnt[owner] += 1;
        }
    }
    grid.sync();

    int nblk = __hip_atomic_load(&regcnt[xcd], __ATOMIC_RELAXED, __HIP_MEMORY_SCOPE_AGENT);
    int nown = owncnt[xcd];

    int wave = tid >> 6;
    int lane = tid & 63;
    int rs   = lane >> 3;
    int u    = lane & 7;

    // half assignment (robust to nblk==1)
    int hfbeg, hfend, mywave, nwh;
    if (nblk >= 2) {
        int hf = slot & 1;
        hfbeg = hf; hfend = hf + 1;
        int nhb = (hf == 0) ? ((nblk + 1) >> 1) : (nblk >> 1);
        mywave = (slot >> 1) * (RNN_THREADS / 64) + wave;
        nwh = nhb * (RNN_THREADS / 64);
    } else {
        hfbeg = 0; hfend = 2;
        mywave = wave; nwh = RNN_THREADS / 64;
    }

    int* bc = &barcnt[xcd * 32];
    int* bgen = &bargen[xcd * 32];

    for (int t = 0; t < T_; ++t) {
        for (int oi = 0; oi < nown; ++oi) {
            int grp = owngrp[xcd * 8 + oi];
            for (int hf = hfbeg; hf < hfend; ++hf) {
                const float* src = hg + (size_t)((grp * 2 + (t & 1)) * 2 + hf) * (H_ * 4);
                float*       dst = hg + (size_t)((grp * 2 + ((t + 1) & 1)) * 2 + hf) * (H_ * 4);

                // ---- fill sh with h_prev (sc0: bypass stale L1, hit local L2) ----
                __syncthreads();   // prior readers of sh are done
                {
                    float4 v0, v1, v2, v3;
                    const float* p0 = src + (size_t)(0 * 1024 + tid) * 4;
                    const float* p1 = src + (size_t)(1 * 1024 + tid) * 4;
                    const float* p2 = src + (size_t)(2 * 1024 + tid) * 4;
                    const float* p3 = src + (size_t)(3 * 1024 + tid) * 4;
                    load4x16_sc0(p0, p1, p2, p3, v0, v1, v2, v3);
                    float4* s4 = (float4*)sh;
                    s4[0 * 1024 + tid] = v0;
                    s4[1 * 1024 + tid] = v1;
                    s4[2 * 1024 + tid] = v2;
                    s4[3 * 1024 + tid] = v3;
                }
                __syncthreads();   // sh ready

                // ---- compute: hh SpMM rows + pre + tanh ----
                for (int g = mywave; g < H_ / 8; g += nwh) {
                    int r  = g * 8 + rs;
                    int hb = hhp[r], he = hhp[r + 1];
                    int len = he - hb;
                    int lmax = len;
                    lmax = max(lmax, __shfl_xor(lmax, 8));
                    lmax = max(lmax, __shfl_xor(lmax, 16));
                    lmax = max(lmax, __shfl_xor(lmax, 32));

                    float a0 = 0.f, a1 = 0.f, a2 = 0.f, a3 = 0.f;
                    int kk = hb + u;
                    for (int i = 0; i < lmax; i += 8, kk += 8) {
                        int2 pk = make_int2(0, 0);
                        if (i + u < len) pk = hhpack[kk];
                        float4 hv = ((const float4*)sh)[pk.x];
                        float v = __int_as_float(pk.y);
                        a0 += v * hv.x; a1 += v * hv.y; a2 += v * hv.z; a3 += v * hv.w;
                    }
                    #pragma unroll
                    for (int off = 1; off <= 4; off <<= 1) {
                        a0 += __shfl_xor(a0, off);
                        a1 += __shfl_xor(a1, off);
                        a2 += __shfl_xor(a2, off);
                        a3 += __shfl_xor(a3, off);
                    }
                    if (u < 4) {
                        float acc = (u == 0) ? a0 : (u == 1) ? a1 : (u == 2) ? a2 : a3;
                        float pv = __uint_as_float(
                            (unsigned int)pre[((size_t)(grp * 2 + hf) * T_ + t) * (H_ * 4) +
                                              (size_t)r * 4 + u] << 16);
                        float h = tanhf(acc + pv);
                        dst[(size_t)r * 4 + u] = h;
                        int b = grp * 8 + hf * 4 + u;
                        out[(size_t)b * T_ * H_ + (size_t)t * H_ + r] = h;
                    }
                }
            }
        }

        // ---- per-XCD barrier (no cache maintenance) ----
        __syncthreads();   // drains this block's h stores to L2 (vmcnt(0) before s_barrier)
        if (tid == 0) {
            asm volatile("s_waitcnt vmcnt(0)" ::: "memory");
            int target = t + 1;
            int old = __hip_atomic_fetch_add(bc, 1, __ATOMIC_RELAXED,
                                             __HIP_MEMORY_SCOPE_AGENT);
            if (old == nblk - 1) {
                __hip_atomic_store(bc, 0, __ATOMIC_RELAXED, __HIP_MEMORY_SCOPE_AGENT);
                __hip_atomic_store(bgen, target, __ATOMIC_RELAXED, __HIP_MEMORY_SCOPE_AGENT);
            } else {
                while (__hip_atomic_load(bgen, __ATOMIC_RELAXED,
                                         __HIP_MEMORY_SCOPE_AGENT) < target) {
                    __builtin_amdgcn_s_sleep(1);
                }
            }
        }
        __syncthreads();
    }
}

// ---------------- host launch ----------------
extern "C" void kernel_launch(void* const* d_in, const int* in_sizes, int n_in,
                              void* d_out, int out_size, void* d_ws, size_t ws_size,
                              hipStream_t stream) {
    const float* x       = (const float*)d_in[0];
    const float* ih_vals = (const float*)d_in[1];
    const float* hh_vals = (const float*)d_in[2];
    const float* hh_bias = (const float*)d_in[3];
    const int*   ih_rows = (const int*)d_in[4];
    const int*   ih_cols = (const int*)d_in[5];
    const int*   hh_rows = (const int*)d_in[6];
    const int*   hh_cols = (const int*)d_in[7];
    float* out = (float*)d_out;

    const int nnz_ih = in_sizes[1];
    const int nnz_hh = in_sizes[2];

    char* ws = (char*)d_ws;
    size_t off = 0;
    auto alloc = [&](size_t bytes) -> void* {
        off = (off + 255) & ~(size_t)255;
        void* p = ws + off;
        off += bytes;
        return p;
    };

    float* xT2   = (float*)alloc((size_t)T_ * 8 * I_ * 8 * sizeof(float));
    int*   ih_rp = (int*)  alloc((H_ + 1) * sizeof(int));
    int*   hh_rp = (int*)  alloc((H_ + 1) * sizeof(int));

    const int ZINTS = 4 * H_ + 64 + 8 * 32 + 8 * 32 + 8 + 64;
    int* zbase  = (int*)alloc((size_t)ZINTS * sizeof(int));
    int* ih_cnt = zbase;
    int* ih_cur = zbase + H_;
    int* hh_cnt = zbase + 2 * H_;
    int* hh_cur = zbase + 3 * H_;
    int* regcnt = zbase + 4 * H_;
    int* barcnt = regcnt + 64;
    int* bargen = barcnt + 8 * 32;
    int* owncnt = bargen + 8 * 32;
    int* owngrp = owncnt + 8;

    int2* ih_pack = (int2*)alloc((size_t)nnz_ih * sizeof(int2));
    int2* hh_pack = (int2*)alloc((size_t)nnz_hh * sizeof(int2));
    float* hg     = (float*)alloc((size_t)XCDS * 2 * 2 * H_ * 4 * sizeof(float));  // 2 MB
    unsigned short* pre = (unsigned short*)alloc((size_t)16 * T_ * H_ * 4 * sizeof(unsigned short)); // 67 MB

    hipMemsetAsync(zbase, 0, (size_t)ZINTS * sizeof(int), stream);
    hipMemsetAsync(hg, 0, (size_t)XCDS * 2 * 2 * H_ * 4 * sizeof(float), stream);

    transpose_x<<<dim3(I_ / 128, 8, T_), dim3(128, 8), 0, stream>>>(x, xT2);

    hist_rows<<<(nnz_ih + 255) / 256, 256, 0, stream>>>(ih_rows, nnz_ih, ih_cnt);
    scan_rows<<<1, 64, 0, stream>>>(ih_cnt, ih_rp, H_);
    scatter_pack<<<(nnz_ih + 255) / 256, 256, 0, stream>>>(ih_rows, ih_cols, ih_vals, nnz_ih,
                                                           ih_rp, ih_cur, ih_pack);
    hist_rows<<<(nnz_hh + 255) / 256, 256, 0, stream>>>(hh_rows, nnz_hh, hh_cnt);
    scan_rows<<<1, 64, 0, stream>>>(hh_cnt, hh_rp, H_);
    scatter_pack<<<(nnz_hh + 255) / 256, 256, 0, stream>>>(hh_rows, hh_cols, hh_vals, nnz_hh,
                                                           hh_rp, hh_cur, hh_pack);

    precompute_ih<<<dim3(H_ / 32, 8, T_), dim3(256), 0, stream>>>(xT2, ih_rp, ih_pack,
                                                                  hh_bias, pre);

    void* kargs[] = {
        (void*)&hh_rp, (void*)&hh_pack,
        (void*)&pre,
        (void*)&hg,
        (void*)&regcnt, (void*)&barcnt, (void*)&bargen,
        (void*)&owncnt, (void*)&owngrp,
        (void*)&out,
    };
    hipLaunchCooperativeKernel((const void*)rnn_steps, dim3(RNN_BLOCKS), dim3(RNN_THREADS),
                               kargs, 0, stream);
}